// Round 7
// baseline (530.768 us; speedup 1.0000x reference)
//
#include <hip/hip_runtime.h>
#include <cmath>
#include <cstdint>

#define NROWS 65536
#define DIMN  256
#define NRF   256
#define OUTD  1024
#define KDIM  1024   // 4*NRF
#define MCOEF 0.001f

typedef __bf16 v8bf __attribute__((ext_vector_type(8)));
typedef float  v4f  __attribute__((ext_vector_type(4)));
typedef unsigned short us8 __attribute__((ext_vector_type(8)));

__device__ __forceinline__ unsigned short f2bf(float f) {
  unsigned int u = __float_as_uint(f);
  u += 0x7fffu + ((u >> 16) & 1u);   // round-to-nearest-even
  return (unsigned short)(u >> 16);
}

__device__ __forceinline__ void async_copy16(const void* g, void* l) {
  __builtin_amdgcn_global_load_lds(
      (const __attribute__((address_space(1))) void*)g,
      (__attribute__((address_space(3))) void*)l, 16, 0, 0);
}

// XOR-swizzled tile layout (16-row fragment reads: conflict-free, measured R3).
__device__ __forceinline__ int sw_slot(int r, int c) {
  return r * 4 + ((c ^ (r >> 1)) & 3);
}

// proj -> bf16, and mg2[i] = M * ||proj_i||^2 (fp32)
__global__ __launch_bounds__(64) void prep_rf(
    const float* __restrict__ proj, unsigned short* __restrict__ projbf,
    float* __restrict__ mg2) {
  int i = blockIdx.x;
  int lane = threadIdx.x;  // 64 threads
  float4 v = ((const float4*)(proj + (size_t)i * DIMN))[lane];
  ushort4 o;
  o.x = f2bf(v.x); o.y = f2bf(v.y); o.z = f2bf(v.z); o.w = f2bf(v.w);
  ((ushort4*)(projbf + (size_t)i * DIMN))[lane] = o;
  float ss = v.x * v.x + v.y * v.y + v.z * v.z + v.w * v.w;
#pragma unroll
  for (int off = 32; off > 0; off >>= 1) ss += __shfl_down(ss, off, 64);
  if (lane == 0) mg2[i] = MCOEF * ss;
}

// Fused feature kernel for BOTH x (blocks 16..1039) and weights (blocks 0..15).
// K layout INTERLEAVED: column k = 4*rf + component (identical F and Wp).
// Software-pipelined A-path + direct ushort4 epilogue stores. FROZEN (R6).
__global__ __launch_bounds__(256) void fused_features(
    const float* __restrict__ srcX,          // 65536 x 256 fp32
    const float* __restrict__ srcW,          // 1024 x 256 fp32
    const float* __restrict__ biasW,         // raw b (scaled by 0.25 here)
    const float* __restrict__ xr_g, const float* __restrict__ xi_g,
    const float* __restrict__ mg2_g,
    const unsigned short* __restrict__ projbf,  // 256 x 256 bf16
    unsigned short* __restrict__ FX,         // 65536 x 1024 bf16
    unsigned short* __restrict__ FW,         // 1024 x 1024 bf16
    float sRx, float sRw, float scaleC) {
  __shared__ __align__(16) unsigned short As[2][64 * 32];    // 2 x 4 KB
  __shared__ __align__(16) unsigned short Bs[2][256 * 32];   // 2 x 16 KB
  __shared__ float xr_s[256], xi_s[256], c1_s[256], c2_s[256], mg2_s[256];
  __shared__ float sq_s[64], bias_s[64];

  int t = threadIdx.x;
  int lane = t & 63;
  int w = t >> 6;

  bool isW = blockIdx.x < (OUTD / 64);
  int blockRow = isW ? blockIdx.x * 64 : (blockIdx.x - OUTD / 64) * 64;
  const float* src = isW ? srcW : srcX;
  float scl = isW ? 0.25f : (1.f / DIMN);
  unsigned short* Fout = isW ? FW : FX;
  float sR = isW ? sRw : sRx;
  float sI = isW ? -sRw : sRx;

  {
    float a = xr_g[t], b = xi_g[t];
    xr_s[t] = a; xi_s[t] = b;
    c1_s[t] = a * a - b * b;   // Re(z^2)
    c2_s[t] = 2.f * a * b;     // Im(z^2)
    mg2_s[t] = mg2_g[t];
  }
  if (t < 64) bias_s[t] = isW ? biasW[blockRow + t] * 0.25f : 0.f;

  v4f acc[4][4];
#pragma unroll
  for (int a = 0; a < 4; a++)
#pragma unroll
    for (int b = 0; b < 4; b++)
#pragma unroll
      for (int q = 0; q < 4; q++) acc[a][b][q] = 0.f;

  int arow = t >> 2, sub = t & 3;
  const float* srow = src + (size_t)(blockRow + arow) * DIMN + sub * 8;
  float ss = 0.f;

  auto stageB = [&](int nb, int kb) {
#pragma unroll
    for (int r = 0; r < 4; r++) {
      int idx = r * 256 + t;
      int row = idx >> 2, kc = ((idx & 3) ^ ((idx >> 3) & 3)) * 8;
      async_copy16(projbf + (size_t)row * DIMN + kb + kc,
                   &Bs[nb][(idx & ~63) * 8]);
    }
  };
  auto cvtA = [&](int nb, float4 v0, float4 v1) {
    v0.x *= scl; v0.y *= scl; v0.z *= scl; v0.w *= scl;
    v1.x *= scl; v1.y *= scl; v1.z *= scl; v1.w *= scl;
    ss += v0.x * v0.x + v0.y * v0.y + v0.z * v0.z + v0.w * v0.w +
          v1.x * v1.x + v1.y * v1.y + v1.z * v1.z + v1.w * v1.w;
    us8 o;
    o[0] = f2bf(v0.x); o[1] = f2bf(v0.y); o[2] = f2bf(v0.z); o[3] = f2bf(v0.w);
    o[4] = f2bf(v1.x); o[5] = f2bf(v1.y); o[6] = f2bf(v1.z); o[7] = f2bf(v1.w);
    *(us8*)&As[nb][sw_slot(arow, sub) * 8] = o;
  };

  stageB(0, 0);
  {
    float4 p0 = *(const float4*)(srow);
    float4 p1 = *(const float4*)(srow + 4);
    cvtA(0, p0, p1);
  }
  __syncthreads();

  for (int kb = 0; kb < 8; kb++) {
    int cur = kb & 1, nb = cur ^ 1;
    float4 n0, n1;
    if (kb < 7) {
      n0 = *(const float4*)(srow + (kb + 1) * 32);
      n1 = *(const float4*)(srow + (kb + 1) * 32 + 4);
      stageB(nb, (kb + 1) * 32);
    }
    v8bf af[4], bfv[4];
    int c = lane >> 4;
#pragma unroll
    for (int mi = 0; mi < 4; mi++)
      af[mi] = *(const v8bf*)&As[cur][sw_slot(mi * 16 + (lane & 15), c) * 8];
#pragma unroll
    for (int ni = 0; ni < 4; ni++)
      bfv[ni] = *(const v8bf*)&Bs[cur][sw_slot(w * 64 + ni * 16 + (lane & 15), c) * 8];
#pragma unroll
    for (int mi = 0; mi < 4; mi++)
#pragma unroll
      for (int ni = 0; ni < 4; ni++)
        acc[mi][ni] = __builtin_amdgcn_mfma_f32_16x16x32_bf16(
            af[mi], bfv[ni], acc[mi][ni], 0, 0, 0);
    if (kb < 7) cvtA(nb, n0, n1);
    __syncthreads();
  }

  ss += __shfl_xor(ss, 1, 64);
  ss += __shfl_xor(ss, 2, 64);
  if (sub == 0) sq_s[arow] = ss;
  __syncthreads();

#pragma unroll
  for (int mi = 0; mi < 4; mi++)
#pragma unroll
    for (int ni = 0; ni < 4; ni++) {
      int i = w * 64 + ni * 16 + (lane & 15);  // rf index
      float xrv = xr_s[i], xiv = xi_s[i];
      float c1v = c1_s[i], c2v = c2_s[i], mgv = mg2_s[i];
#pragma unroll
      for (int reg = 0; reg < 4; reg++) {
        int rglob = mi * 16 + (lane >> 4) * 4 + reg;   // row within block
        float px = acc[mi][ni][reg];
        float tt = scaleC * px + bias_s[rglob];
        float u  = 0.5f * sq_s[rglob];
        float aa = u * c1v + mgv;
        float bb = u * c2v;
        float txr = tt * xrv;
        float txi = tt * xiv;
        float erp = __expf(txr - aa);
        float erm = __expf(-txr - aa);
        float s1, cc1, s2, cc2;
        __sincosf(txi - bb, &s1, &cc1);
        __sincosf(txi + bb, &s2, &cc2);
        ushort4 ov;
        ov.x = f2bf(sR * erp * cc1);
        ov.y = f2bf(sR * erm * cc2);
        ov.z = f2bf(sI * erp * s1);
        ov.w = f2bf(-sI * erm * s2);
        *(ushort4*)(Fout + (size_t)(blockRow + rglob) * KDIM + 4 * i) = ov;
      }
    }
}

// ---------------------------------------------------------------------------
// 256x256 4-phase GEMM, BK=32, 2 BLOCKS/CU (LDS 64 KB). Same verified
// skeleton (row-permuted halves, pre-swizzled source, counted vmcnt, raw
// barriers, setprio) with re-derived constants for BK=32:
//   half = 128 rows x 32 k = 8 KB = 1 global_load_lds per thread
//   row = 64 B = 4 chunks; swizzle swz(r) = (r ^ (r>>2)) & 3  => every
//   16-row fragment read hits each bank-granule residue exactly 2x (2-way
//   = free, m136). Steady-state outstanding oscillates 2..4; WAITV(2) at
//   P1/P2/P4 (never 0 until epilogue).
// Rationale: at 128 KB LDS (1 block/CU) every barrier drain + the per-round
// 64 KB C-write burst is exposed; a second resident block hides them (m114).
//   A-frag (16x16x32): row = lane&15, chunk = lane>>4
//   C/D: col = lane&15, row = (lane>>4)*4 + reg
// ---------------------------------------------------------------------------
#define WAITV(N) asm volatile("s_waitcnt vmcnt(" #N ")" ::: "memory")

__global__ __launch_bounds__(512) void gemm_bt(
    const unsigned short* __restrict__ A,   // NROWS x KDIM bf16
    const unsigned short* __restrict__ B,   // OUTD x KDIM bf16
    float* __restrict__ C) {                // NROWS x OUTD fp32
  __shared__ __align__(16) unsigned short As[2][256 * 32];   // 2 x 16 KB
  __shared__ __align__(16) unsigned short Bs[2][256 * 32];   // 2 x 16 KB
  int tt = threadIdx.x;
  int lane = tt & 63;
  int wv = tt >> 6;
  int wm = wv >> 2, wn = wv & 3;           // 2 x 4 wave grid

  // XCD-aware bijective swizzle (1024 % 8 == 0)
  int lid = blockIdx.x;
  int wg = (lid & 7) * 128 + (lid >> 3);
  size_t bm = (size_t)(wg >> 2) * 256;
  size_t bn = (size_t)(wg & 3) * 256;

  // Per-thread staging source offsets (elements), 1 load per half.
  // Linear granule L = tt in a half holds (row r = L>>2, slot s = L&3);
  // slot s stores global chunk c = s ^ swz(r).
  // Row permutation (LDS rho = h*128+r -> global row), phase-aligned halves:
  //   A: rho = mh*128 + wm*64 + rr <-> g = wm*128 + mh*64 + rr
  //   B: rho = nh*128 + wn*32 + j  <-> g = wn*64  + nh*32 + j
  unsigned int offA[2], offB[2];
#pragma unroll
  for (int h = 0; h < 2; h++) {
    int r = tt >> 2, s = tt & 3;
    int c = s ^ ((r ^ (r >> 2)) & 3);
    int rho = h * 128 + r;
    int gA = ((rho >> 6) & 1) * 128 + (rho >> 7) * 64 + (rho & 63);
    int gB = ((rho >> 5) & 3) * 64 + (rho >> 7) * 32 + (rho & 31);
    offA[h] = (unsigned int)((bm + gA) * KDIM + c * 8);
    offB[h] = (unsigned int)((bn + gB) * KDIM + c * 8);
  }

#define STAGE_A(H, KB) \
  async_copy16(A + offA[H] + (KB), &As[nbuf][((H) * 512 + (tt & ~63)) * 8])
#define STAGE_B(H, KB) \
  async_copy16(B + offB[H] + (KB), &Bs[nbuf][((H) * 512 + (tt & ~63)) * 8])

  v8bf af[4], b0[2], b1[2];
  v4f acc[8][4];
#pragma unroll
  for (int a = 0; a < 8; a++)
#pragma unroll
    for (int b = 0; b < 4; b++)
#pragma unroll
      for (int q = 0; q < 4; q++) acc[a][b][q] = 0.f;

  int ch = lane >> 4;                      // fragment k-chunk 0..3
#define READ_A(MH) do { \
  _Pragma("unroll") for (int mf_ = 0; mf_ < 4; mf_++) { \
    int r_ = wm * 64 + mf_ * 16 + (lane & 15); \
    int g_ = (MH) * 512 + r_ * 4 + (ch ^ ((r_ ^ (r_ >> 2)) & 3)); \
    af[mf_] = *(const v8bf*)&As[buf][g_ * 8]; \
  } \
} while (0)
#define READ_B(NH, DST) do { \
  _Pragma("unroll") for (int nf_ = 0; nf_ < 2; nf_++) { \
    int r_ = wn * 32 + nf_ * 16 + (lane & 15); \
    int g_ = (NH) * 512 + r_ * 4 + (ch ^ ((r_ ^ (r_ >> 2)) & 3)); \
    DST[nf_] = *(const v8bf*)&Bs[buf][g_ * 8]; \
  } \
} while (0)
#define MMA_Q(MH, NH, BSRC) do { \
  __builtin_amdgcn_s_setprio(1); \
  _Pragma("unroll") for (int mf_ = 0; mf_ < 4; mf_++) \
  _Pragma("unroll") for (int nf_ = 0; nf_ < 2; nf_++) \
    acc[(MH) * 4 + mf_][(NH) * 2 + nf_] = \
        __builtin_amdgcn_mfma_f32_16x16x32_bf16( \
            af[mf_], BSRC[nf_], acc[(MH) * 4 + mf_][(NH) * 2 + nf_], 0, 0, 0); \
  __builtin_amdgcn_s_setprio(0); \
} while (0)

  // Prologue: stage tile 0 into buf 0 (order Ah0, Bh0, Bh1, Ah1 = 4 loads).
  {
    const int nbuf = 0;
    STAGE_A(0, 0); STAGE_B(0, 0); STAGE_B(1, 0); STAGE_A(1, 0);
  }
  WAITV(2);                         // Ah0 + Bh0 landed (2 still in flight)
  __builtin_amdgcn_s_barrier();

  for (int t = 0; t < 32; ++t) {
    const int buf = t & 1, nbuf = buf ^ 1;
    const bool pf = (t < 31);
    const int kb = (t + 1) * 32;

    // P1: read Ah0+Bh0 frags, stage Ah0(next), MFMA Q(0,0). Next need: Bh1c.
    READ_A(0); READ_B(0, b0);
    if (pf) STAGE_A(0, kb);
    __builtin_amdgcn_s_barrier();
    MMA_Q(0, 0, b0);
    if (pf) { WAITV(2); } else { WAITV(1); }
    __builtin_amdgcn_s_barrier();

    // P2: read Bh1 frags, stage Bh0(next), MFMA Q(0,1). Next need: Ah1c.
    READ_B(1, b1);
    if (pf) STAGE_B(0, kb);
    __builtin_amdgcn_s_barrier();
    MMA_Q(0, 1, b1);
    if (pf) { WAITV(2); } else { WAITV(0); }
    __builtin_amdgcn_s_barrier();

    // P3: read Ah1 frags, stage Bh1(next), MFMA Q(1,1). P4 reads regs only.
    READ_A(1);
    if (pf) STAGE_B(1, kb);
    __builtin_amdgcn_s_barrier();
    MMA_Q(1, 1, b1);
    __builtin_amdgcn_s_barrier();

    // P4: stage Ah1(next), MFMA Q(1,0). Next tile P1 needs Ah0n+Bh0n.
    if (pf) STAGE_A(1, kb);
    __builtin_amdgcn_s_barrier();
    MMA_Q(1, 0, b0);
    if (pf) { WAITV(2); }
    __builtin_amdgcn_s_barrier();
  }

#pragma unroll
  for (int mf = 0; mf < 8; mf++)
#pragma unroll
    for (int nf = 0; nf < 4; nf++)
#pragma unroll
      for (int reg = 0; reg < 4; reg++) {
        size_t row = bm + wm * 128 + mf * 16 + (lane >> 4) * 4 + reg;
        size_t col = bn + wn * 64 + nf * 16 + (lane & 15);
        C[row * OUTD + col] = acc[mf][nf][reg];
      }
#undef STAGE_A
#undef STAGE_B
#undef READ_A
#undef READ_B
#undef MMA_Q
}

extern "C" void kernel_launch(void* const* d_in, const int* in_sizes, int n_in,
                              void* d_out, int out_size, void* d_ws, size_t ws_size,
                              hipStream_t stream) {
  (void)in_sizes; (void)n_in; (void)out_size;
  const float* x    = (const float*)d_in[0];
  const float* iw   = (const float*)d_in[1];
  const float* bvec = (const float*)d_in[2];
  const float* proj = (const float*)d_in[3];
  const float* xr   = (const float*)d_in[4];
  const float* xi   = (const float*)d_in[5];
  float* out = (float*)d_out;

  char* ws = (char*)d_ws;
  size_t off = 0;
  auto take = [&](size_t bytes) {
    char* p = ws + off;
    off = (off + bytes + 255) & ~(size_t)255;
    return p;
  };
  unsigned short* F      = (unsigned short*)take((size_t)NROWS * KDIM * 2);  // 134 MB
  unsigned short* Wp     = (unsigned short*)take((size_t)OUTD * KDIM * 2);   // 2 MB
  unsigned short* projbf = (unsigned short*)take((size_t)NRF * DIMN * 2);    // 128 KB
  float* mg2 = (float*)take((size_t)NRF * 4);
  if (ws_size < off) return;

  const float  scaleC = sqrtf(1.f + 4.f * MCOEF);
  const double c2d    = 0.5 * exp(128.0 * log(1.0 + 4.0 * 0.001));
  const float  invSR  = 0.0625f;
  const float  sRw    = (float)(c2d * 0.0625);

  prep_rf<<<NRF, 64, 0, stream>>>(proj, projbf, mg2);
  fused_features<<<NROWS / 64 + OUTD / 64, 256, 0, stream>>>(
      x, iw, bvec, xr, xi, mg2, projbf, F, Wp, invSR, sRw, scaleC);
  gemm_bt<<<1024, 512, 0, stream>>>(F, Wp, out);
}